// Round 7
// baseline (153.659 us; speedup 1.0000x reference)
//
#include <hip/hip_runtime.h>
#include <math.h>

#define NPOS 4096   // H*W
#define NB   4      // batch
#define NROW (NB * NPOS)
#define LOG2E 1.44269504088896f

typedef _Float16 f16;
typedef f16 f16x4 __attribute__((ext_vector_type(4)));
typedef f16 f16x8 __attribute__((ext_vector_type(8)));
typedef float f32x4 __attribute__((ext_vector_type(4)));

// ---------------------------------------------------------------------------
// Kernel 1: QKV projection as MFMA GEMM, 16-position tiles -> 1024 blocks
// (4 blocks/CU). q pre-scaled by log2(e); pos bias folded into k; v -> [c][n].
// ---------------------------------------------------------------------------
#define LDW 72

__global__ __launch_bounds__(256) void qkv_proj(
    const float* __restrict__ x,
    const float* __restrict__ Wq, const float* __restrict__ bq,
    const float* __restrict__ Wk, const float* __restrict__ bk,
    const float* __restrict__ Wv, const float* __restrict__ bv,
    const float* __restrict__ rel_h, const float* __restrict__ rel_w,
    f16* __restrict__ qh, f16* __restrict__ kh, f16* __restrict__ vh)
{
    __shared__ __align__(16) f16 Ws[192 * LDW];  // [o_all][c]
    __shared__ __align__(16) f16 Xs[16 * LDW];   // [n_local][c]
    __shared__ __align__(16) f16 Vs[64 * 20];    // v transpose buffer [c][n_local]

    const int tid = threadIdx.x;
    const int b   = blockIdx.x >> 8;           // 256 tiles per batch
    const int n0  = (blockIdx.x & 255) << 4;   // 16-position tile

    #pragma unroll
    for (int k = 0; k < 12; ++k) {
        int idx  = tid + k * 256;
        int orow = idx >> 4;
        int cseg = (idx & 15) << 2;
        int mat  = orow >> 6;
        int o    = orow & 63;
        const float* wsrc = (mat == 0) ? Wq : ((mat == 1) ? Wk : Wv);
        float4 v = *(const float4*)(wsrc + o * 64 + cseg);
        f16x4 h; h[0] = (f16)v.x; h[1] = (f16)v.y; h[2] = (f16)v.z; h[3] = (f16)v.w;
        *(f16x4*)(&Ws[orow * LDW + cseg]) = h;
    }
    {
        int c  = tid >> 2;
        int ns = (tid & 3) << 2;
        float4 v = *(const float4*)(x + ((size_t)(b * 64 + c)) * NPOS + n0 + ns);
        Xs[(ns + 0) * LDW + c] = (f16)v.x;
        Xs[(ns + 1) * LDW + c] = (f16)v.y;
        Xs[(ns + 2) * LDW + c] = (f16)v.z;
        Xs[(ns + 3) * LDW + c] = (f16)v.w;
    }
    __syncthreads();

    const int wave = tid >> 6;
    const int lane = tid & 63;
    const int quad = lane >> 4;
    const int l16  = lane & 15;

    const f16x8 a0 = *(const f16x8*)(&Xs[l16 * LDW + quad * 8]);
    const f16x8 a1 = *(const f16x8*)(&Xs[l16 * LDW + 32 + quad * 8]);

    f32x4 acc[3];
    const int t0 = wave * 3;
    #pragma unroll
    for (int i = 0; i < 3; ++i) {
        int t = t0 + i;
        f32x4 c0 = {0, 0, 0, 0};
        f16x8 b0 = *(const f16x8*)(&Ws[(t * 16 + l16) * LDW + quad * 8]);
        f16x8 b1 = *(const f16x8*)(&Ws[(t * 16 + l16) * LDW + 32 + quad * 8]);
        c0 = __builtin_amdgcn_mfma_f32_16x16x32_f16(a0, b0, c0, 0, 0, 0);
        c0 = __builtin_amdgcn_mfma_f32_16x16x32_f16(a1, b1, c0, 0, 0, 0);
        acc[i] = c0;
    }

    #pragma unroll
    for (int i = 0; i < 3; ++i) {
        int t = t0 + i;
        if (t < 4) {                       // q tiles
            int o = t * 16 + l16;
            float bb = bq[o];
            #pragma unroll
            for (int r = 0; r < 4; ++r) {
                size_t n = (size_t)b * NPOS + n0 + quad * 4 + r;
                qh[n * 64 + o] = (f16)((acc[i][r] + bb) * LOG2E);
            }
        } else if (t < 8) {                // k tiles (+ positional bias)
            int o = (t - 4) * 16 + l16;
            int h = n0 >> 6;               // 16-tiles never straddle a row of 64
            int wbase = n0 & 63;
            float bb = bk[o] + rel_h[o * 64 + h];
            #pragma unroll
            for (int r = 0; r < 4; ++r) {
                size_t n = (size_t)b * NPOS + n0 + quad * 4 + r;
                kh[n * 64 + o] = (f16)(acc[i][r] + bb + rel_w[o * 64 + wbase + quad * 4 + r]);
            }
        } else {                           // v tiles -> LDS transpose
            int o = (t - 8) * 16 + l16;
            float bb = bv[o];
            #pragma unroll
            for (int r = 0; r < 4; ++r)
                Vs[o * 20 + quad * 4 + r] = (f16)(acc[i][r] + bb);
        }
    }
    __syncthreads();
    {
        int c  = tid >> 2;
        int ns = (tid & 3) << 2;
        f16x4 vv = *(const f16x4*)(&Vs[c * 20 + ns]);
        *(f16x4*)(vh + ((size_t)(b * 64 + c)) * NPOS + n0 + ns) = vv;
    }
}

// ---------------------------------------------------------------------------
// Kernel 2: flash attention via S^T = K Q^T.
// Round-7: attn was LDS-pipe-bound (~256 LDS cyc/wave/iter, 4x wave-redundant
// K/V fragment reads). Changes:
//   - K A-fragments load DIRECTLY from global (coalesced dwordx4, L2-hot);
//     K never touches LDS -> -96 LDS cyc/wave/iter, no K staging.
//   - V double-buffered in LDS (2 x 9216 B, 8 blocks/CU): stage next tile
//     before PV of current -> ONE barrier per iteration.
//   - P stays in registers (S^T C-layout == 16x16x16 A-frag); conditional
//     O-rescale via wave-uniform __any.
// ---------------------------------------------------------------------------
#define LDV 72

__global__ __launch_bounds__(256, 8) void attn(
    const f16* __restrict__ qh, const f16* __restrict__ kh,
    const f16* __restrict__ vh,
    f16* __restrict__ Op, float* __restrict__ Mp, float* __restrict__ Lp,
    int split, int mchunk)
{
    __shared__ __align__(16) f16 Vt[2][64 * LDV];   // V-tile [c][m_local]

    const int tid  = threadIdx.x;
    const int wave = tid >> 6;
    const int lane = tid & 63;
    const int quad = lane >> 4;
    const int l16  = lane & 15;
    const int s    = blockIdx.x % split;
    const int tile = blockIdx.x / split;
    const int b    = tile >> 6;
    const int n0   = (tile & 63) << 6;

    // Q as B-operand: B[quad*8+j][l16] = Q[n=l16][c=quad*8+j]
    const f16* qbase = qh + ((size_t)b * NPOS + n0 + wave * 16 + l16) * 64;
    const f16x8 bq0 = *(const f16x8*)(qbase + quad * 8);
    const f16x8 bq1 = *(const f16x8*)(qbase + 32 + quad * 8);

    f32x4 O[4] = {{0,0,0,0},{0,0,0,0},{0,0,0,0},{0,0,0,0}};
    float m_i = -1e30f, l_i = 0.f;

    const int vrow = tid >> 2;          // 0..63 (c)
    const int vseg = (tid & 3) * 16;    // halves within 64-m row
    const f16* kb = kh + (size_t)b * NPOS * 64;
    const f16* vb = vh + (size_t)b * 64 * NPOS;

    const int m_begin = s * mchunk;
    const int m_end   = m_begin + mchunk;

    // prologue: stage first V tile into buf 0
    {
        const f16* vsrc = vb + (size_t)vrow * NPOS + m_begin + vseg;
        *(f16x8*)(&Vt[0][vrow * LDV + vseg])     = *(const f16x8*)(vsrc);
        *(f16x8*)(&Vt[0][vrow * LDV + vseg + 8]) = *(const f16x8*)(vsrc + 8);
    }
    __syncthreads();

    int buf = 0;
    for (int m0 = m_begin; m0 < m_end; m0 += 64) {
        // stage NEXT V tile into the other buffer (no barrier needed yet)
        if (m0 + 64 < m_end) {
            const f16* vsrc = vb + (size_t)vrow * NPOS + (m0 + 64) + vseg;
            *(f16x8*)(&Vt[buf ^ 1][vrow * LDV + vseg])     = *(const f16x8*)(vsrc);
            *(f16x8*)(&Vt[buf ^ 1][vrow * LDV + vseg + 8]) = *(const f16x8*)(vsrc + 8);
        }

        // S^T = K Q^T — K A-fragments straight from global (dwordx4, L2-hot)
        f32x4 S[4];
        #pragma unroll
        for (int t = 0; t < 4; ++t) {
            const f16* krow = kb + (size_t)(m0 + t * 16 + l16) * 64;
            f16x8 ak0 = *(const f16x8*)(krow + quad * 8);
            f16x8 ak1 = *(const f16x8*)(krow + 32 + quad * 8);
            f32x4 acc = {0, 0, 0, 0};
            acc = __builtin_amdgcn_mfma_f32_16x16x32_f16(ak0, bq0, acc, 0, 0, 0);
            acc = __builtin_amdgcn_mfma_f32_16x16x32_f16(ak1, bq1, acc, 0, 0, 0);
            S[t] = acc;
        }

        // column max (n = l16): 15 in-lane fmax + 2 shuffles
        float mx = S[0][0];
        #pragma unroll
        for (int t = 0; t < 4; ++t)
            #pragma unroll
            for (int r = 0; r < 4; ++r) mx = fmaxf(mx, S[t][r]);
        mx = fmaxf(mx, __shfl_xor(mx, 16));
        mx = fmaxf(mx, __shfl_xor(mx, 32));

        // conditional rescale (wave-uniform skip once max is stable)
        if (__any(mx > m_i)) {
            float mnew  = fmaxf(m_i, mx);
            float alpha = __builtin_amdgcn_exp2f(m_i - mnew);
            m_i = mnew;
            l_i *= alpha;
            #pragma unroll
            for (int r = 0; r < 4; ++r) {
                float av = __shfl(alpha, quad * 20 + r);  // lane owning column quad*4+r
                O[0][r] *= av; O[1][r] *= av; O[2][r] *= av; O[3][r] *= av;
            }
        }

        // exp2 + pack A-fragments + row-sum
        float rs = 0.f;
        f16x4 pa[4];
        #pragma unroll
        for (int t = 0; t < 4; ++t) {
            f16x4 a;
            #pragma unroll
            for (int r = 0; r < 4; ++r) {
                float e = __builtin_amdgcn_exp2f(S[t][r] - m_i);
                rs += e;
                a[r] = (f16)e;
            }
            pa[t] = a;
        }
        rs += __shfl_xor(rs, 16);
        rs += __shfl_xor(rs, 32);
        l_i += rs;

        // O += P V  (4 c-tiles x 4 m-steps of 16x16x16) from current buffer
        #pragma unroll
        for (int u = 0; u < 4; ++u) {
            #pragma unroll
            for (int t = 0; t < 4; ++t) {
                f16x4 bf = *(const f16x4*)(&Vt[buf][(u * 16 + l16) * LDV + t * 16 + quad * 4]);
                O[u] = __builtin_amdgcn_mfma_f32_16x16x16f16(pa[t], bf, O[u], 0, 0, 0);
            }
        }
        __syncthreads();   // next tile fully staged; current fully consumed
        buf ^= 1;
    }

    // partial epilogue
    #pragma unroll
    for (int r = 0; r < 4; ++r) {
        float lr  = __shfl(l_i, quad * 20 + r);
        float inv = 1.f / lr;
        size_t row = (size_t)b * NPOS + n0 + wave * 16 + quad * 4 + r;
        #pragma unroll
        for (int u = 0; u < 4; ++u)
            Op[((size_t)s * NROW + row) * 64 + u * 16 + l16] = (f16)(O[u][r] * inv);
    }
    if (lane < 16) {
        size_t row = (size_t)b * NPOS + n0 + wave * 16 + l16;
        Mp[(size_t)s * NROW + row] = m_i;
        Lp[(size_t)s * NROW + row] = l_i;
    }
}

// ---------------------------------------------------------------------------
// Kernel 3: combine split partials. grid 1024 (16-row tiles, 4 blocks/CU).
// ---------------------------------------------------------------------------
__global__ __launch_bounds__(256) void combine(
    const f16* __restrict__ Op, const float* __restrict__ Mp,
    const float* __restrict__ Lp, float* __restrict__ out, int split)
{
    __shared__ float Ot[16 * 68];   // [n_local][c] padded

    const int tid = threadIdx.x;
    const int b   = blockIdx.x >> 8;            // 256 tiles of 16 rows per batch
    const int n0  = (blockIdx.x & 255) << 4;

    {
        int nl = tid >> 4;            // 0..15 row within tile
        int cs = (tid & 15) << 2;     // 4-channel chunk
        size_t row = (size_t)b * NPOS + n0 + nl;

        float M = -1e30f;
        for (int s2 = 0; s2 < split; ++s2)
            M = fmaxf(M, Mp[(size_t)s2 * NROW + row]);

        float L = 0.f;
        float val[4] = {0.f, 0.f, 0.f, 0.f};
        for (int s2 = 0; s2 < split; ++s2) {
            float w = Lp[(size_t)s2 * NROW + row] *
                      __builtin_amdgcn_exp2f(Mp[(size_t)s2 * NROW + row] - M);
            L += w;
            f16x4 o0 = *(const f16x4*)(Op + ((size_t)s2 * NROW + row) * 64 + cs);
            #pragma unroll
            for (int j = 0; j < 4; ++j) val[j] += w * (float)o0[j];
        }
        float invL = 1.f / L;
        float4 v4 = { val[0] * invL, val[1] * invL, val[2] * invL, val[3] * invL };
        *(float4*)(&Ot[nl * 68 + cs]) = v4;
    }
    __syncthreads();
    {
        int c  = tid >> 2;            // 0..63
        int ns = (tid & 3) << 2;      // 0..12
        float4 v4 = { Ot[(ns + 0) * 68 + c], Ot[(ns + 1) * 68 + c],
                      Ot[(ns + 2) * 68 + c], Ot[(ns + 3) * 68 + c] };
        *(float4*)(out + ((size_t)(b * 64 + c)) * NPOS + n0 + ns) = v4;
    }
}

// ---------------------------------------------------------------------------
extern "C" void kernel_launch(void* const* d_in, const int* in_sizes, int n_in,
                              void* d_out, int out_size, void* d_ws, size_t ws_size,
                              hipStream_t stream) {
    const float* x     = (const float*)d_in[0];
    const float* Wq    = (const float*)d_in[1];
    const float* bq    = (const float*)d_in[2];
    const float* Wk    = (const float*)d_in[3];
    const float* bk    = (const float*)d_in[4];
    const float* Wv    = (const float*)d_in[5];
    const float* bv    = (const float*)d_in[6];
    const float* rel_h = (const float*)d_in[7];
    const float* rel_w = (const float*)d_in[8];
    float* out = (float*)d_out;

    const size_t qkv_elems = (size_t)NROW * 64;
    int split = 8;
    {
        size_t need = 3 * qkv_elems * sizeof(f16)
                    + (size_t)split * NROW * 64 * sizeof(f16)
                    + 2 * (size_t)split * NROW * sizeof(float);
        if (ws_size < need) split = 4;     // deterministic wrt ws_size
    }
    const int mchunk = NPOS / split;

    f16* qh = (f16*)d_ws;
    f16* kh = qh + qkv_elems;
    f16* vh = kh + qkv_elems;
    f16* Op = vh + qkv_elems;
    float* Mp = (float*)(Op + (size_t)split * NROW * 64);
    float* Lp = Mp + (size_t)split * NROW;

    qkv_proj<<<NB * (NPOS / 16), 256, 0, stream>>>(x, Wq, bq, Wk, bk, Wv, bv,
                                                   rel_h, rel_w, qh, kh, vh);
    attn<<<NB * (NPOS / 64) * split, 256, 0, stream>>>(qh, kh, vh, Op, Mp, Lp,
                                                       split, mchunk);
    combine<<<NB * (NPOS / 16), 256, 0, stream>>>(Op, Mp, Lp, out, split);
}

// Round 8
// 117.518 us; speedup vs baseline: 1.3075x; 1.3075x over previous
//
#include <hip/hip_runtime.h>
#include <math.h>

#define NPOS 4096   // H*W
#define NB   4      // batch
#define NROW (NB * NPOS)
#define LOG2E 1.44269504088896f

typedef _Float16 f16;
typedef f16 f16x4 __attribute__((ext_vector_type(4)));
typedef f16 f16x8 __attribute__((ext_vector_type(8)));
typedef float f32x4 __attribute__((ext_vector_type(4)));

// ---------------------------------------------------------------------------
// Kernel 1: QKV projection as MFMA GEMM, 16-position tiles -> 1024 blocks
// (4 blocks/CU). q pre-scaled by log2(e); pos bias folded into k; v -> [c][n].
// ---------------------------------------------------------------------------
#define LDW 72

__global__ __launch_bounds__(256) void qkv_proj(
    const float* __restrict__ x,
    const float* __restrict__ Wq, const float* __restrict__ bq,
    const float* __restrict__ Wk, const float* __restrict__ bk,
    const float* __restrict__ Wv, const float* __restrict__ bv,
    const float* __restrict__ rel_h, const float* __restrict__ rel_w,
    f16* __restrict__ qh, f16* __restrict__ kh, f16* __restrict__ vh)
{
    __shared__ __align__(16) f16 Ws[192 * LDW];  // [o_all][c]
    __shared__ __align__(16) f16 Xs[16 * LDW];   // [n_local][c]
    __shared__ __align__(16) f16 Vs[64 * 20];    // v transpose buffer [c][n_local]

    const int tid = threadIdx.x;
    const int b   = blockIdx.x >> 8;           // 256 tiles per batch
    const int n0  = (blockIdx.x & 255) << 4;   // 16-position tile

    #pragma unroll
    for (int k = 0; k < 12; ++k) {
        int idx  = tid + k * 256;
        int orow = idx >> 4;
        int cseg = (idx & 15) << 2;
        int mat  = orow >> 6;
        int o    = orow & 63;
        const float* wsrc = (mat == 0) ? Wq : ((mat == 1) ? Wk : Wv);
        float4 v = *(const float4*)(wsrc + o * 64 + cseg);
        f16x4 h; h[0] = (f16)v.x; h[1] = (f16)v.y; h[2] = (f16)v.z; h[3] = (f16)v.w;
        *(f16x4*)(&Ws[orow * LDW + cseg]) = h;
    }
    {
        int c  = tid >> 2;
        int ns = (tid & 3) << 2;
        float4 v = *(const float4*)(x + ((size_t)(b * 64 + c)) * NPOS + n0 + ns);
        Xs[(ns + 0) * LDW + c] = (f16)v.x;
        Xs[(ns + 1) * LDW + c] = (f16)v.y;
        Xs[(ns + 2) * LDW + c] = (f16)v.z;
        Xs[(ns + 3) * LDW + c] = (f16)v.w;
    }
    __syncthreads();

    const int wave = tid >> 6;
    const int lane = tid & 63;
    const int quad = lane >> 4;
    const int l16  = lane & 15;

    const f16x8 a0 = *(const f16x8*)(&Xs[l16 * LDW + quad * 8]);
    const f16x8 a1 = *(const f16x8*)(&Xs[l16 * LDW + 32 + quad * 8]);

    f32x4 acc[3];
    const int t0 = wave * 3;
    #pragma unroll
    for (int i = 0; i < 3; ++i) {
        int t = t0 + i;
        f32x4 c0 = {0, 0, 0, 0};
        f16x8 b0 = *(const f16x8*)(&Ws[(t * 16 + l16) * LDW + quad * 8]);
        f16x8 b1 = *(const f16x8*)(&Ws[(t * 16 + l16) * LDW + 32 + quad * 8]);
        c0 = __builtin_amdgcn_mfma_f32_16x16x32_f16(a0, b0, c0, 0, 0, 0);
        c0 = __builtin_amdgcn_mfma_f32_16x16x32_f16(a1, b1, c0, 0, 0, 0);
        acc[i] = c0;
    }

    #pragma unroll
    for (int i = 0; i < 3; ++i) {
        int t = t0 + i;
        if (t < 4) {                       // q tiles
            int o = t * 16 + l16;
            float bb = bq[o];
            #pragma unroll
            for (int r = 0; r < 4; ++r) {
                size_t n = (size_t)b * NPOS + n0 + quad * 4 + r;
                qh[n * 64 + o] = (f16)((acc[i][r] + bb) * LOG2E);
            }
        } else if (t < 8) {                // k tiles (+ positional bias)
            int o = (t - 4) * 16 + l16;
            int h = n0 >> 6;               // 16-tiles never straddle a row of 64
            int wbase = n0 & 63;
            float bb = bk[o] + rel_h[o * 64 + h];
            #pragma unroll
            for (int r = 0; r < 4; ++r) {
                size_t n = (size_t)b * NPOS + n0 + quad * 4 + r;
                kh[n * 64 + o] = (f16)(acc[i][r] + bb + rel_w[o * 64 + wbase + quad * 4 + r]);
            }
        } else {                           // v tiles -> LDS transpose
            int o = (t - 8) * 16 + l16;
            float bb = bv[o];
            #pragma unroll
            for (int r = 0; r < 4; ++r)
                Vs[o * 20 + quad * 4 + r] = (f16)(acc[i][r] + bb);
        }
    }
    __syncthreads();
    {
        int c  = tid >> 2;
        int ns = (tid & 3) << 2;
        f16x4 vv = *(const f16x4*)(&Vs[c * 20 + ns]);
        *(f16x4*)(vh + ((size_t)(b * 64 + c)) * NPOS + n0 + ns) = vv;
    }
}

// ---------------------------------------------------------------------------
// Kernel 2: flash attention via S^T = K Q^T  (round-8: 2x Q-rows per wave).
// Block covers 128 Q-positions; wave w owns n-strips [w*32, w*32+16) and
// [w*32+16, w*32+32). K A-frags and V B-frags are GROUP-INVARIANT: read once
// from LDS, used for both groups -> per-CU LDS cycles halve vs r6 (which was
// LDS-issue-bound: ~256 LDS cyc/wave/iter vs ~77 MFMA cyc).
// K/V staged in LDS (r7 lesson: K-from-global = L2-latency + 4x redundant
// traffic, regressed 48->74 us). Grid 1024 = 4 blocks/CU exactly resident.
// ---------------------------------------------------------------------------
#define LDP 72

__global__ __launch_bounds__(256, 4) void attn(
    const f16* __restrict__ qh, const f16* __restrict__ kh,
    const f16* __restrict__ vh,
    f16* __restrict__ Op, float* __restrict__ Mp, float* __restrict__ Lp,
    int split, int mchunk)
{
    __shared__ __align__(16) f16 Ks[64 * LDP];   // K-tile [m_local][c]
    __shared__ __align__(16) f16 Vt[64 * LDP];   // V-tile [c][m_local]

    const int tid  = threadIdx.x;
    const int wave = tid >> 6;
    const int lane = tid & 63;
    const int quad = lane >> 4;
    const int l16  = lane & 15;
    const int s    = blockIdx.x % split;
    const int tile = blockIdx.x / split;
    const int b    = tile >> 5;                 // 32 tiles of 128 per batch
    const int n0   = (tile & 31) << 7;

    // Q B-fragments for both 16-n groups: B[quad*8+j][l16] = Q[n][c=quad*8+j]
    f16x8 bq0[2], bq1[2];
    #pragma unroll
    for (int g = 0; g < 2; ++g) {
        const f16* qbase = qh + ((size_t)b * NPOS + n0 + wave * 32 + g * 16 + l16) * 64;
        bq0[g] = *(const f16x8*)(qbase + quad * 8);
        bq1[g] = *(const f16x8*)(qbase + 32 + quad * 8);
    }

    f32x4 O[2][4] = {{{0,0,0,0},{0,0,0,0},{0,0,0,0},{0,0,0,0}},
                     {{0,0,0,0},{0,0,0,0},{0,0,0,0},{0,0,0,0}}};
    float m_i[2] = {-1e30f, -1e30f}, l_i[2] = {0.f, 0.f};

    const int srow = tid >> 2;
    const int sseg = (tid & 3) * 16;
    const f16* kb = kh + (size_t)b * NPOS * 64;
    const f16* vb = vh + (size_t)b * 64 * NPOS;

    const int m_begin = s * mchunk;
    for (int m0 = m_begin; m0 < m_begin + mchunk; m0 += 64) {
        const f16* ksrc = kb + (size_t)(m0 + srow) * 64 + sseg;
        *(f16x8*)(&Ks[srow * LDP + sseg])     = *(const f16x8*)(ksrc);
        *(f16x8*)(&Ks[srow * LDP + sseg + 8]) = *(const f16x8*)(ksrc + 8);
        const f16* vsrc = vb + (size_t)srow * NPOS + m0 + sseg;
        *(f16x8*)(&Vt[srow * LDP + sseg])     = *(const f16x8*)(vsrc);
        *(f16x8*)(&Vt[srow * LDP + sseg + 8]) = *(const f16x8*)(vsrc + 8);
        __syncthreads();

        // S^T = K Q^T for both groups; K A-frags read once per t
        f32x4 S[2][4];
        #pragma unroll
        for (int t = 0; t < 4; ++t) {
            f16x8 ak0 = *(const f16x8*)(&Ks[(t * 16 + l16) * LDP + quad * 8]);
            f16x8 ak1 = *(const f16x8*)(&Ks[(t * 16 + l16) * LDP + 32 + quad * 8]);
            #pragma unroll
            for (int g = 0; g < 2; ++g) {
                f32x4 acc = {0, 0, 0, 0};
                acc = __builtin_amdgcn_mfma_f32_16x16x32_f16(ak0, bq0[g], acc, 0, 0, 0);
                acc = __builtin_amdgcn_mfma_f32_16x16x32_f16(ak1, bq1[g], acc, 0, 0, 0);
                S[g][t] = acc;
            }
        }

        // online softmax per group (column n = group base + l16)
        f16x4 pa[2][4];
        #pragma unroll
        for (int g = 0; g < 2; ++g) {
            float mx = S[g][0][0];
            #pragma unroll
            for (int t = 0; t < 4; ++t)
                #pragma unroll
                for (int r = 0; r < 4; ++r) mx = fmaxf(mx, S[g][t][r]);
            mx = fmaxf(mx, __shfl_xor(mx, 16));
            mx = fmaxf(mx, __shfl_xor(mx, 32));

            if (__any(mx > m_i[g])) {
                float mnew  = fmaxf(m_i[g], mx);
                float alpha = __builtin_amdgcn_exp2f(m_i[g] - mnew);
                m_i[g] = mnew;
                l_i[g] *= alpha;
                #pragma unroll
                for (int r = 0; r < 4; ++r) {
                    float av = __shfl(alpha, quad * 20 + r);
                    O[g][0][r] *= av; O[g][1][r] *= av;
                    O[g][2][r] *= av; O[g][3][r] *= av;
                }
            }

            float rs = 0.f;
            #pragma unroll
            for (int t = 0; t < 4; ++t) {
                f16x4 a;
                #pragma unroll
                for (int r = 0; r < 4; ++r) {
                    float e = __builtin_amdgcn_exp2f(S[g][t][r] - m_i[g]);
                    rs += e;
                    a[r] = (f16)e;
                }
                pa[g][t] = a;
            }
            rs += __shfl_xor(rs, 16);
            rs += __shfl_xor(rs, 32);
            l_i[g] += rs;
        }

        // O += P V; V B-frags read once per (u,t), used for both groups
        #pragma unroll
        for (int u = 0; u < 4; ++u) {
            #pragma unroll
            for (int t = 0; t < 4; ++t) {
                f16x4 bf = *(const f16x4*)(&Vt[(u * 16 + l16) * LDP + t * 16 + quad * 4]);
                O[0][u] = __builtin_amdgcn_mfma_f32_16x16x16f16(pa[0][t], bf, O[0][u], 0, 0, 0);
                O[1][u] = __builtin_amdgcn_mfma_f32_16x16x16f16(pa[1][t], bf, O[1][u], 0, 0, 0);
            }
        }
        __syncthreads();
    }

    // partial epilogue (per group)
    #pragma unroll
    for (int g = 0; g < 2; ++g) {
        #pragma unroll
        for (int r = 0; r < 4; ++r) {
            float lr  = __shfl(l_i[g], quad * 20 + r);
            float inv = 1.f / lr;
            size_t row = (size_t)b * NPOS + n0 + wave * 32 + g * 16 + quad * 4 + r;
            #pragma unroll
            for (int u = 0; u < 4; ++u)
                Op[((size_t)s * NROW + row) * 64 + u * 16 + l16] = (f16)(O[g][u][r] * inv);
        }
        if (lane < 16) {
            size_t row = (size_t)b * NPOS + n0 + wave * 32 + g * 16 + l16;
            Mp[(size_t)s * NROW + row] = m_i[g];
            Lp[(size_t)s * NROW + row] = l_i[g];
        }
    }
}

// ---------------------------------------------------------------------------
// Kernel 3: combine split partials. grid 1024 (16-row tiles, 4 blocks/CU).
// ---------------------------------------------------------------------------
__global__ __launch_bounds__(256) void combine(
    const f16* __restrict__ Op, const float* __restrict__ Mp,
    const float* __restrict__ Lp, float* __restrict__ out, int split)
{
    __shared__ float Ot[16 * 68];   // [n_local][c] padded

    const int tid = threadIdx.x;
    const int b   = blockIdx.x >> 8;            // 256 tiles of 16 rows per batch
    const int n0  = (blockIdx.x & 255) << 4;

    {
        int nl = tid >> 4;            // 0..15 row within tile
        int cs = (tid & 15) << 2;     // 4-channel chunk
        size_t row = (size_t)b * NPOS + n0 + nl;

        float M = -1e30f;
        for (int s2 = 0; s2 < split; ++s2)
            M = fmaxf(M, Mp[(size_t)s2 * NROW + row]);

        float L = 0.f;
        float val[4] = {0.f, 0.f, 0.f, 0.f};
        for (int s2 = 0; s2 < split; ++s2) {
            float w = Lp[(size_t)s2 * NROW + row] *
                      __builtin_amdgcn_exp2f(Mp[(size_t)s2 * NROW + row] - M);
            L += w;
            f16x4 o0 = *(const f16x4*)(Op + ((size_t)s2 * NROW + row) * 64 + cs);
            #pragma unroll
            for (int j = 0; j < 4; ++j) val[j] += w * (float)o0[j];
        }
        float invL = 1.f / L;
        float4 v4 = { val[0] * invL, val[1] * invL, val[2] * invL, val[3] * invL };
        *(float4*)(&Ot[nl * 68 + cs]) = v4;
    }
    __syncthreads();
    {
        int c  = tid >> 2;            // 0..63
        int ns = (tid & 3) << 2;      // 0..12
        float4 v4 = { Ot[(ns + 0) * 68 + c], Ot[(ns + 1) * 68 + c],
                      Ot[(ns + 2) * 68 + c], Ot[(ns + 3) * 68 + c] };
        *(float4*)(out + ((size_t)(b * 64 + c)) * NPOS + n0 + ns) = v4;
    }
}

// ---------------------------------------------------------------------------
extern "C" void kernel_launch(void* const* d_in, const int* in_sizes, int n_in,
                              void* d_out, int out_size, void* d_ws, size_t ws_size,
                              hipStream_t stream) {
    const float* x     = (const float*)d_in[0];
    const float* Wq    = (const float*)d_in[1];
    const float* bq    = (const float*)d_in[2];
    const float* Wk    = (const float*)d_in[3];
    const float* bk    = (const float*)d_in[4];
    const float* Wv    = (const float*)d_in[5];
    const float* bv    = (const float*)d_in[6];
    const float* rel_h = (const float*)d_in[7];
    const float* rel_w = (const float*)d_in[8];
    float* out = (float*)d_out;

    const size_t qkv_elems = (size_t)NROW * 64;
    int split = 8;
    {
        size_t need = 3 * qkv_elems * sizeof(f16)
                    + (size_t)split * NROW * 64 * sizeof(f16)
                    + 2 * (size_t)split * NROW * sizeof(float);
        if (ws_size < need) split = 4;     // deterministic wrt ws_size
    }
    const int mchunk = NPOS / split;

    f16* qh = (f16*)d_ws;
    f16* kh = qh + qkv_elems;
    f16* vh = kh + qkv_elems;
    f16* Op = vh + qkv_elems;
    float* Mp = (float*)(Op + (size_t)split * NROW * 64);
    float* Lp = Mp + (size_t)split * NROW;

    qkv_proj<<<NB * (NPOS / 16), 256, 0, stream>>>(x, Wq, bq, Wk, bk, Wv, bv,
                                                   rel_h, rel_w, qh, kh, vh);
    attn<<<NB * (NPOS / 128) * split, 256, 0, stream>>>(qh, kh, vh, Op, Mp, Lp,
                                                        split, mchunk);
    combine<<<NB * (NPOS / 16), 256, 0, stream>>>(Op, Mp, Lp, out, split);
}

// Round 9
// 116.521 us; speedup vs baseline: 1.3187x; 1.0086x over previous
//
#include <hip/hip_runtime.h>
#include <math.h>

#define NPOS 4096   // H*W
#define NB   4      // batch
#define NROW (NB * NPOS)
#define LOG2E 1.44269504088896f

typedef _Float16 f16;
typedef f16 f16x4 __attribute__((ext_vector_type(4)));
typedef f16 f16x8 __attribute__((ext_vector_type(8)));
typedef float f32x4 __attribute__((ext_vector_type(4)));

// ---------------------------------------------------------------------------
// Kernel 1: QKV projection as MFMA GEMM, 32-position tiles -> 512 blocks
// (2 blocks/CU). W staged once per block (halved vs 16-pos tiles); each wave
// computes 6 of the 24 (row-group x out-tile) jobs.
// q pre-scaled by log2(e); pos bias folded into k; v stored [c][n].
// ---------------------------------------------------------------------------
#define LDW 72

__global__ __launch_bounds__(256) void qkv_proj(
    const float* __restrict__ x,
    const float* __restrict__ Wq, const float* __restrict__ bq,
    const float* __restrict__ Wk, const float* __restrict__ bk,
    const float* __restrict__ Wv, const float* __restrict__ bv,
    const float* __restrict__ rel_h, const float* __restrict__ rel_w,
    f16* __restrict__ qh, f16* __restrict__ kh, f16* __restrict__ vh)
{
    __shared__ __align__(16) f16 Ws[192 * LDW];  // [o_all][c]
    __shared__ __align__(16) f16 Xs[32 * LDW];   // [n_local][c]
    __shared__ __align__(16) f16 Vs[64 * 36];    // v transpose buffer [c][n_local]

    const int tid = threadIdx.x;
    const int b   = blockIdx.x >> 7;           // 128 tiles per batch
    const int n0  = (blockIdx.x & 127) << 5;   // 32-position tile

    // stage W (3 x 64 x 64 fp32 -> f16 row-major)
    #pragma unroll
    for (int k = 0; k < 12; ++k) {
        int idx  = tid + k * 256;
        int orow = idx >> 4;
        int cseg = (idx & 15) << 2;
        int mat  = orow >> 6;
        int o    = orow & 63;
        const float* wsrc = (mat == 0) ? Wq : ((mat == 1) ? Wk : Wv);
        float4 v = *(const float4*)(wsrc + o * 64 + cseg);
        f16x4 h; h[0] = (f16)v.x; h[1] = (f16)v.y; h[2] = (f16)v.z; h[3] = (f16)v.w;
        *(f16x4*)(&Ws[orow * LDW + cseg]) = h;
    }
    // stage X transposed: 32 pos x 64 ch; each thread 8 consecutive n
    {
        int c  = tid >> 2;
        int ns = (tid & 3) << 3;
        const float* xp = x + ((size_t)(b * 64 + c)) * NPOS + n0 + ns;
        float4 v0 = *(const float4*)(xp);
        float4 v1 = *(const float4*)(xp + 4);
        Xs[(ns + 0) * LDW + c] = (f16)v0.x;
        Xs[(ns + 1) * LDW + c] = (f16)v0.y;
        Xs[(ns + 2) * LDW + c] = (f16)v0.z;
        Xs[(ns + 3) * LDW + c] = (f16)v0.w;
        Xs[(ns + 4) * LDW + c] = (f16)v1.x;
        Xs[(ns + 5) * LDW + c] = (f16)v1.y;
        Xs[(ns + 6) * LDW + c] = (f16)v1.z;
        Xs[(ns + 7) * LDW + c] = (f16)v1.w;
    }
    __syncthreads();

    const int wave = tid >> 6;
    const int lane = tid & 63;
    const int quad = lane >> 4;
    const int l16  = lane & 15;
    const int rg   = wave >> 1;                // row-group (16 n each)
    const int tb   = (wave & 1) * 6;           // out-tile base

    const f16x8 a0 = *(const f16x8*)(&Xs[(rg * 16 + l16) * LDW + quad * 8]);
    const f16x8 a1 = *(const f16x8*)(&Xs[(rg * 16 + l16) * LDW + 32 + quad * 8]);

    f32x4 acc[6];
    #pragma unroll
    for (int i = 0; i < 6; ++i) {
        int t = tb + i;
        f32x4 c0 = {0, 0, 0, 0};
        f16x8 b0 = *(const f16x8*)(&Ws[(t * 16 + l16) * LDW + quad * 8]);
        f16x8 b1 = *(const f16x8*)(&Ws[(t * 16 + l16) * LDW + 32 + quad * 8]);
        c0 = __builtin_amdgcn_mfma_f32_16x16x32_f16(a0, b0, c0, 0, 0, 0);
        c0 = __builtin_amdgcn_mfma_f32_16x16x32_f16(a1, b1, c0, 0, 0, 0);
        acc[i] = c0;
    }

    #pragma unroll
    for (int i = 0; i < 6; ++i) {
        int t = tb + i;
        if (t < 4) {                       // q tiles
            int o = t * 16 + l16;
            float bb = bq[o];
            #pragma unroll
            for (int r = 0; r < 4; ++r) {
                size_t n = (size_t)b * NPOS + n0 + rg * 16 + quad * 4 + r;
                qh[n * 64 + o] = (f16)((acc[i][r] + bb) * LOG2E);
            }
        } else if (t < 8) {                // k tiles (+ positional bias)
            int o = (t - 4) * 16 + l16;
            int h = n0 >> 6;               // 32-tiles never straddle a row of 64
            int wbase = (n0 & 63) + rg * 16;
            float bb = bk[o] + rel_h[o * 64 + h];
            #pragma unroll
            for (int r = 0; r < 4; ++r) {
                size_t n = (size_t)b * NPOS + n0 + rg * 16 + quad * 4 + r;
                kh[n * 64 + o] = (f16)(acc[i][r] + bb + rel_w[o * 64 + wbase + quad * 4 + r]);
            }
        } else {                           // v tiles -> LDS transpose
            int o = (t - 8) * 16 + l16;
            float bb = bv[o];
            #pragma unroll
            for (int r = 0; r < 4; ++r)
                Vs[o * 36 + rg * 16 + quad * 4 + r] = (f16)(acc[i][r] + bb);
        }
    }
    __syncthreads();
    {
        int c  = tid >> 2;
        int ns = (tid & 3) << 3;
        f16x8 vv = *(const f16x8*)(&Vs[c * 36 + ns]);
        *(f16x8*)(vh + ((size_t)(b * 64 + c)) * NPOS + n0 + ns) = vv;
    }
}

// ---------------------------------------------------------------------------
// Kernel 2: flash attention via S^T = K Q^T, 2 Q-groups/wave (128-Q blocks),
// round-9: 128 m-rows staged per barrier-pair (two 64-m compute passes) ->
// barrier count halves vs r8. K/V in LDS (r7 lesson: K-from-global regressed).
// K A-frags / V B-frags are group-invariant: read once, used for both groups.
// LDS 4 x 9216 B = 36864 -> 4 blocks/CU.
// ---------------------------------------------------------------------------
#define LDP 72

__global__ __launch_bounds__(256, 4) void attn(
    const f16* __restrict__ qh, const f16* __restrict__ kh,
    const f16* __restrict__ vh,
    f16* __restrict__ Op, float* __restrict__ Mp, float* __restrict__ Lp,
    int split, int mchunk)
{
    __shared__ __align__(16) f16 Ks[2][64 * LDP];   // K-tiles [m_local][c]
    __shared__ __align__(16) f16 Vt[2][64 * LDP];   // V-tiles [c][m_local]

    const int tid  = threadIdx.x;
    const int wave = tid >> 6;
    const int lane = tid & 63;
    const int quad = lane >> 4;
    const int l16  = lane & 15;
    const int s    = blockIdx.x % split;
    const int tile = blockIdx.x / split;
    const int b    = tile >> 5;                 // 32 tiles of 128 per batch
    const int n0   = (tile & 31) << 7;

    // Q B-fragments for both 16-n groups: B[quad*8+j][l16] = Q[n][c=quad*8+j]
    f16x8 bq0[2], bq1[2];
    #pragma unroll
    for (int g = 0; g < 2; ++g) {
        const f16* qbase = qh + ((size_t)b * NPOS + n0 + wave * 32 + g * 16 + l16) * 64;
        bq0[g] = *(const f16x8*)(qbase + quad * 8);
        bq1[g] = *(const f16x8*)(qbase + 32 + quad * 8);
    }

    f32x4 O[2][4] = {{{0,0,0,0},{0,0,0,0},{0,0,0,0},{0,0,0,0}},
                     {{0,0,0,0},{0,0,0,0},{0,0,0,0},{0,0,0,0}}};
    float m_i[2] = {-1e30f, -1e30f}, l_i[2] = {0.f, 0.f};

    const int srow = tid >> 2;
    const int sseg = (tid & 3) * 16;
    const f16* kb = kh + (size_t)b * NPOS * 64;
    const f16* vb = vh + (size_t)b * 64 * NPOS;

    const int m_begin = s * mchunk;
    for (int m0 = m_begin; m0 < m_begin + mchunk; m0 += 128) {
        // stage both 64-m halves (one barrier-pair per 128 m)
        #pragma unroll
        for (int h = 0; h < 2; ++h) {
            const f16* ksrc = kb + (size_t)(m0 + h * 64 + srow) * 64 + sseg;
            *(f16x8*)(&Ks[h][srow * LDP + sseg])     = *(const f16x8*)(ksrc);
            *(f16x8*)(&Ks[h][srow * LDP + sseg + 8]) = *(const f16x8*)(ksrc + 8);
            const f16* vsrc = vb + (size_t)srow * NPOS + m0 + h * 64 + sseg;
            *(f16x8*)(&Vt[h][srow * LDP + sseg])     = *(const f16x8*)(vsrc);
            *(f16x8*)(&Vt[h][srow * LDP + sseg + 8]) = *(const f16x8*)(vsrc + 8);
        }
        __syncthreads();

        #pragma unroll
        for (int h = 0; h < 2; ++h) {
            // S^T = K Q^T for both groups; K A-frags read once per t
            f32x4 S[2][4];
            #pragma unroll
            for (int t = 0; t < 4; ++t) {
                f16x8 ak0 = *(const f16x8*)(&Ks[h][(t * 16 + l16) * LDP + quad * 8]);
                f16x8 ak1 = *(const f16x8*)(&Ks[h][(t * 16 + l16) * LDP + 32 + quad * 8]);
                #pragma unroll
                for (int g = 0; g < 2; ++g) {
                    f32x4 acc = {0, 0, 0, 0};
                    acc = __builtin_amdgcn_mfma_f32_16x16x32_f16(ak0, bq0[g], acc, 0, 0, 0);
                    acc = __builtin_amdgcn_mfma_f32_16x16x32_f16(ak1, bq1[g], acc, 0, 0, 0);
                    S[g][t] = acc;
                }
            }

            // online softmax per group (column n = group base + l16)
            f16x4 pa[2][4];
            #pragma unroll
            for (int g = 0; g < 2; ++g) {
                float mx = S[g][0][0];
                #pragma unroll
                for (int t = 0; t < 4; ++t)
                    #pragma unroll
                    for (int r = 0; r < 4; ++r) mx = fmaxf(mx, S[g][t][r]);
                mx = fmaxf(mx, __shfl_xor(mx, 16));
                mx = fmaxf(mx, __shfl_xor(mx, 32));

                if (__any(mx > m_i[g])) {
                    float mnew  = fmaxf(m_i[g], mx);
                    float alpha = __builtin_amdgcn_exp2f(m_i[g] - mnew);
                    m_i[g] = mnew;
                    l_i[g] *= alpha;
                    #pragma unroll
                    for (int r = 0; r < 4; ++r) {
                        float av = __shfl(alpha, quad * 20 + r);
                        O[g][0][r] *= av; O[g][1][r] *= av;
                        O[g][2][r] *= av; O[g][3][r] *= av;
                    }
                }

                float rs = 0.f;
                #pragma unroll
                for (int t = 0; t < 4; ++t) {
                    f16x4 a;
                    #pragma unroll
                    for (int r = 0; r < 4; ++r) {
                        float e = __builtin_amdgcn_exp2f(S[g][t][r] - m_i[g]);
                        rs += e;
                        a[r] = (f16)e;
                    }
                    pa[g][t] = a;
                }
                rs += __shfl_xor(rs, 16);
                rs += __shfl_xor(rs, 32);
                l_i[g] += rs;
            }

            // O += P V; V B-frags read once per (u,t), used for both groups
            #pragma unroll
            for (int u = 0; u < 4; ++u) {
                #pragma unroll
                for (int t = 0; t < 4; ++t) {
                    f16x4 bf = *(const f16x4*)(&Vt[h][(u * 16 + l16) * LDP + t * 16 + quad * 4]);
                    O[0][u] = __builtin_amdgcn_mfma_f32_16x16x16f16(pa[0][t], bf, O[0][u], 0, 0, 0);
                    O[1][u] = __builtin_amdgcn_mfma_f32_16x16x16f16(pa[1][t], bf, O[1][u], 0, 0, 0);
                }
            }
        }
        __syncthreads();
    }

    // partial epilogue (per group)
    #pragma unroll
    for (int g = 0; g < 2; ++g) {
        #pragma unroll
        for (int r = 0; r < 4; ++r) {
            float lr  = __shfl(l_i[g], quad * 20 + r);
            float inv = 1.f / lr;
            size_t row = (size_t)b * NPOS + n0 + wave * 32 + g * 16 + quad * 4 + r;
            #pragma unroll
            for (int u = 0; u < 4; ++u)
                Op[((size_t)s * NROW + row) * 64 + u * 16 + l16] = (f16)(O[g][u][r] * inv);
        }
        if (lane < 16) {
            size_t row = (size_t)b * NPOS + n0 + wave * 32 + g * 16 + l16;
            Mp[(size_t)s * NROW + row] = m_i[g];
            Lp[(size_t)s * NROW + row] = l_i[g];
        }
    }
}

// ---------------------------------------------------------------------------
// Kernel 3: combine split partials. grid 1024 (16-row tiles, 4 blocks/CU).
// ---------------------------------------------------------------------------
__global__ __launch_bounds__(256) void combine(
    const f16* __restrict__ Op, const float* __restrict__ Mp,
    const float* __restrict__ Lp, float* __restrict__ out, int split)
{
    __shared__ float Ot[16 * 68];   // [n_local][c] padded

    const int tid = threadIdx.x;
    const int b   = blockIdx.x >> 8;            // 256 tiles of 16 rows per batch
    const int n0  = (blockIdx.x & 255) << 4;

    {
        int nl = tid >> 4;            // 0..15 row within tile
        int cs = (tid & 15) << 2;     // 4-channel chunk
        size_t row = (size_t)b * NPOS + n0 + nl;

        float M = -1e30f;
        for (int s2 = 0; s2 < split; ++s2)
            M = fmaxf(M, Mp[(size_t)s2 * NROW + row]);

        float L = 0.f;
        float val[4] = {0.f, 0.f, 0.f, 0.f};
        for (int s2 = 0; s2 < split; ++s2) {
            float w = Lp[(size_t)s2 * NROW + row] *
                      __builtin_amdgcn_exp2f(Mp[(size_t)s2 * NROW + row] - M);
            L += w;
            f16x4 o0 = *(const f16x4*)(Op + ((size_t)s2 * NROW + row) * 64 + cs);
            #pragma unroll
            for (int j = 0; j < 4; ++j) val[j] += w * (float)o0[j];
        }
        float invL = 1.f / L;
        float4 v4 = { val[0] * invL, val[1] * invL, val[2] * invL, val[3] * invL };
        *(float4*)(&Ot[nl * 68 + cs]) = v4;
    }
    __syncthreads();
    {
        int c  = tid >> 2;            // 0..63
        int ns = (tid & 3) << 2;      // 0..12
        float4 v4 = { Ot[(ns + 0) * 68 + c], Ot[(ns + 1) * 68 + c],
                      Ot[(ns + 2) * 68 + c], Ot[(ns + 3) * 68 + c] };
        *(float4*)(out + ((size_t)(b * 64 + c)) * NPOS + n0 + ns) = v4;
    }
}

// ---------------------------------------------------------------------------
extern "C" void kernel_launch(void* const* d_in, const int* in_sizes, int n_in,
                              void* d_out, int out_size, void* d_ws, size_t ws_size,
                              hipStream_t stream) {
    const float* x     = (const float*)d_in[0];
    const float* Wq    = (const float*)d_in[1];
    const float* bq    = (const float*)d_in[2];
    const float* Wk    = (const float*)d_in[3];
    const float* bk    = (const float*)d_in[4];
    const float* Wv    = (const float*)d_in[5];
    const float* bv    = (const float*)d_in[6];
    const float* rel_h = (const float*)d_in[7];
    const float* rel_w = (const float*)d_in[8];
    float* out = (float*)d_out;

    const size_t qkv_elems = (size_t)NROW * 64;
    int split = 8;
    {
        size_t need = 3 * qkv_elems * sizeof(f16)
                    + (size_t)split * NROW * 64 * sizeof(f16)
                    + 2 * (size_t)split * NROW * sizeof(float);
        if (ws_size < need) split = 4;     // deterministic wrt ws_size
    }
    const int mchunk = NPOS / split;       // multiple of 128

    f16* qh = (f16*)d_ws;
    f16* kh = qh + qkv_elems;
    f16* vh = kh + qkv_elems;
    f16* Op = vh + qkv_elems;
    float* Mp = (float*)(Op + (size_t)split * NROW * 64);
    float* Lp = Mp + (size_t)split * NROW;

    qkv_proj<<<NB * (NPOS / 32), 256, 0, stream>>>(x, Wq, bq, Wk, bk, Wv, bv,
                                                   rel_h, rel_w, qh, kh, vh);
    attn<<<NB * (NPOS / 128) * split, 256, 0, stream>>>(qh, kh, vh, Op, Mp, Lp,
                                                        split, mchunk);
    combine<<<NB * (NPOS / 16), 256, 0, stream>>>(Op, Mp, Lp, out, split);
}